// Round 1
// baseline (371.767 us; speedup 1.0000x reference)
//
#include <hip/hip_runtime.h>
#include <hip/hip_bf16.h>

#define DEV static __device__ __forceinline__

// ---------------- problem constants ----------------
constexpr int BB  = 64;      // batch
constexpr int NN  = 16;      // nodes
constexpr int DD  = 64;      // channels
constexpr int PP  = 5;       // spatial
constexpr int DSS = 32;      // attn channels
constexpr int IMG = BB * NN;         // 1024 images
constexpr int PIX = PP * PP;         // 25
constexpr int IE  = DD * PIX;        // 1600 floats per image
constexpr float INV_TEMP = 0.035355339059327376f;  // 1/sqrt(32*25)

// padded LDS image tile: [c][7][8]; image stride padded (+8) so 4 image
// groups land on distinct bank offsets {0,8,16,24}
constexpr int CST = 56;              // channel stride (7 rows * 8)
constexpr int IST = DD * CST + 8;    // 3592 floats per image

// ---------------- workspace layout (floats) ----------------
constexpr size_t OFF_WTU    = 0;                        // 64*64*12
constexpr size_t OFF_WTV    = OFF_WTU    + 49152;
constexpr size_t OFF_WTSELF = OFF_WTV    + 49152;
constexpr size_t OFF_WTAFF  = OFF_WTSELF + 49152;
constexpr size_t OFF_WTAGA  = OFF_WTAFF  + 49152;
constexpr size_t OFF_WTAGS  = OFF_WTAGA  + 49152;
constexpr size_t OFF_WTQ    = OFF_WTAGS  + 49152;       // 32*32*12
constexpr size_t OFF_WTK    = OFF_WTQ    + 12288;
constexpr size_t OFF_WTATT  = OFF_WTK    + 12288;       // 64*32  [c][ds]
constexpr size_t OFF_Q      = OFF_WTATT  + 2048;        // 1024*800
constexpr size_t OFF_K      = OFF_Q      + 819200;
constexpr size_t OFF_SM     = OFF_K      + 819200;      // 64*16*16
constexpr size_t OFF_U      = OFF_SM     + 16384;       // 1024*1600
constexpr size_t OFF_V      = OFF_U      + 1638400;
constexpr size_t OFF_XS     = OFF_V      + 1638400;
constexpr size_t OFF_A      = OFF_XS     + 1638400;
constexpr size_t OFF_SUMS   = OFF_A      + 1638400;     // 64*2

// ---------------- K0: weight transpose to [c][o][12] ----------------
__global__ __launch_bounds__(256) void k0_transpose(
    const float* __restrict__ w_rel, const float* __restrict__ w_self,
    const float* __restrict__ w_aff, const float* __restrict__ w_agg,
    const float* __restrict__ w_q,   const float* __restrict__ w_k,
    const float* __restrict__ w_attn, float* __restrict__ ws) {
  int idx = blockIdx.x * 256 + threadIdx.x;
  const int C64 = 64 * 64 * 12;   // 49152
  if (idx < 6 * C64) {
    int a = idx / C64, r = idx % C64;
    int c = r / (64 * 12); int o = (r / 12) % 64; int t = r % 12;
    float v = 0.f;
    if (t < 9) {
      switch (a) {
        case 0: v = w_rel [(o * 128 + c) * 9 + t];       break;  // u part
        case 1: v = w_rel [(o * 128 + 64 + c) * 9 + t];  break;  // v part
        case 2: v = w_self[(o * 64 + c) * 9 + t];        break;
        case 3: v = w_aff [(o * 64 + c) * 9 + t];        break;
        case 4: v = w_agg [(o * 128 + c) * 9 + t];       break;  // a_norm part
        case 5: v = w_agg [(o * 128 + 64 + c) * 9 + t];  break;  // s part
      }
    }
    ws[idx] = v;
    return;
  }
  idx -= 6 * C64;
  const int C32 = 32 * 32 * 12;   // 12288
  if (idx < 2 * C32) {
    int a = idx / C32, r = idx % C32;
    int c = r / (32 * 12); int o = (r / 12) % 32; int t = r % 12;
    float v = 0.f;
    if (t < 9) v = (a == 0 ? w_q : w_k)[(o * 32 + c) * 9 + t];
    ws[6 * C64 + idx] = v;
    return;
  }
  idx -= 2 * C32;
  if (idx < 2048) {
    int c = idx / 32, ds = idx % 32;
    ws[6 * C64 + 2 * C32 + idx] = w_attn[ds * 64 + c];
  }
}

// ---------------- conv core: accumulate one image's conv for one output ch
// xb: LDS base of padded image [C][7][8]; wt layout [c][o][12]
template <int C>
DEV void convC_acc(const float* xb, const float* __restrict__ wt, int o,
                   float acc[5][5]) {
#pragma unroll 2
  for (int c = 0; c < C; ++c) {
    float pr[7][8];
#pragma unroll
    for (int r = 0; r < 7; ++r) {
      float4 a = *(const float4*)(xb + c * CST + r * 8);
      float4 b = *(const float4*)(xb + c * CST + r * 8 + 4);
      pr[r][0] = a.x; pr[r][1] = a.y; pr[r][2] = a.z; pr[r][3] = a.w;
      pr[r][4] = b.x; pr[r][5] = b.y; pr[r][6] = b.z; pr[r][7] = b.w;
    }
    const float* wp = wt + (size_t)(c * C + o) * 12;
    float4 w0 = *(const float4*)wp;
    float4 w1 = *(const float4*)(wp + 4);
    float ww[9] = {w0.x, w0.y, w0.z, w0.w, w1.x, w1.y, w1.z, w1.w, wp[8]};
#pragma unroll
    for (int ky = 0; ky < 3; ++ky)
#pragma unroll
      for (int kx = 0; kx < 3; ++kx) {
        float w = ww[ky * 3 + kx];
#pragma unroll
        for (int y = 0; y < 5; ++y)
#pragma unroll
          for (int xx = 0; xx < 5; ++xx)
            acc[y][xx] = fmaf(w, pr[y + ky][xx + kx], acc[y][xx]);
      }
  }
}

DEV void acc_init(float acc[5][5], float b) {
#pragma unroll
  for (int y = 0; y < 5; ++y)
#pragma unroll
    for (int xx = 0; xx < 5; ++xx) acc[y][xx] = b;
}

// ---------------- K1: s2d (1x1) + q/k 3x3 convs, 2 images/block ----------
__global__ __launch_bounds__(128) void k1_qk(
    const float* __restrict__ x, const float* __restrict__ b_attn,
    const float* __restrict__ b_q, const float* __restrict__ b_k,
    float* __restrict__ ws) {
  __shared__ float xr[2 * IE];                 // [img][c][pix]
  __shared__ float s2dp[2][DSS][7][8];         // padded, halo zero
  __shared__ float watt[64 * DSS];
  int tid = threadIdx.x;
  int img0 = blockIdx.x * 2;
  for (int i = tid; i < 2 * IE; i += 128) xr[i] = x[(size_t)img0 * IE + i];
  for (int i = tid; i < 64 * DSS; i += 128) watt[i] = ws[OFF_WTATT + i];
  float* sp = &s2dp[0][0][0][0];
  for (int i = tid; i < 2 * DSS * CST; i += 128) sp[i] = 0.f;
  __syncthreads();
  for (int idx = tid; idx < 2 * DSS * PIX; idx += 128) {
    int img = idx / (DSS * PIX); int r = idx % (DSS * PIX);
    int ds = r / PIX; int pix = r % PIX;
    float acc = b_attn[ds];
    const float* xc = &xr[img * IE + pix];
#pragma unroll 8
    for (int c = 0; c < 64; ++c) acc += watt[c * DSS + ds] * xc[c * PIX];
    s2dp[img][ds][pix / 5 + 1][pix % 5 + 1] = acc;   // no relu on s2d
  }
  __syncthreads();
  int wave = tid >> 6, lane = tid & 63;
  int img = lane >> 5, o = lane & 31;
  const float* wt = ws + (wave ? OFF_WTK : OFF_WTQ);
  float bb = wave ? b_k[o] : b_q[o];
  float* outp = ws + (wave ? OFF_K : OFF_Q) + (size_t)(img0 + img) * 800 + o * PIX;
  float acc[5][5];
  acc_init(acc, bb);
  convC_acc<32>(&s2dp[img][0][0][0], wt, o, acc);
#pragma unroll
  for (int y = 0; y < 5; ++y)
#pragma unroll
    for (int xx = 0; xx < 5; ++xx)
      outp[y * 5 + xx] = fmaxf(acc[y][xx], 0.f);     // relu(q/k)
}

// ---------------- K2: attn logits + softmax (+ zero LN sums) -------------
__global__ __launch_bounds__(256) void k2_attn(float* __restrict__ ws) {
  __shared__ float kb[16][804];
  __shared__ float att[16][17];
  __shared__ float rowm[16], rows[16];
  int b = blockIdx.x, tid = threadIdx.x;
  const float* kg = ws + OFF_K + (size_t)b * 16 * 800;
  for (int i = tid; i < 12800; i += 256) kb[i / 800][i % 800] = kg[i];
  if (tid < 2) ws[OFF_SUMS + b * 2 + tid] = 0.f;
  __syncthreads();
  int i = tid >> 4, j = tid & 15;
  const float* qr = ws + OFF_Q + (size_t)(b * 16 + i) * 800;
  float acc = 0.f;
  for (int f = 0; f < 800; f += 4) {
    float4 a = *(const float4*)(qr + f);
    float4 c = *(const float4*)&kb[j][f];
    acc += a.x * c.x + a.y * c.y + a.z * c.z + a.w * c.w;
  }
  att[i][j] = acc * INV_TEMP;
  __syncthreads();
  if (tid < 16) {
    float m = att[tid][0];
    for (int jj = 1; jj < 16; ++jj) m = fmaxf(m, att[tid][jj]);
    float s = 0.f;
    for (int jj = 0; jj < 16; ++jj) s += expf(att[tid][jj] - m);
    rowm[tid] = m; rows[tid] = 1.f / s;
  }
  __syncthreads();
  ws[OFF_SM + (size_t)b * 256 + tid] = expf(att[i][j] - rowm[i]) * rows[i];
}

// ---------------- K3: u, v, xs convs fused; 4 images/block ---------------
__global__ __launch_bounds__(256) void k3_uvxs(
    const float* __restrict__ x, const float* __restrict__ b_rel,
    const float* __restrict__ b_self, float* __restrict__ ws) {
  __shared__ float xp[4 * IST];
  int tid = threadIdx.x;
  int img0 = blockIdx.x * 4;
  for (int i = tid; i < 4 * IST; i += 256) xp[i] = 0.f;
  __syncthreads();
  for (int i = tid; i < 4 * IE; i += 256) {
    int k = i / IE, e = i % IE, c = e / PIX, pix = e % PIX;
    xp[k * IST + c * CST + (pix / 5 + 1) * 8 + pix % 5 + 1] =
        x[(size_t)img0 * IE + i];
  }
  __syncthreads();
  int wave = tid >> 6, lane = tid & 63;
  int img = lane >> 4, o = wave * 16 + (lane & 15);
  const float* xb = &xp[img * IST];
  size_t gout = (size_t)(img0 + img) * IE + o * PIX;
  float acc[5][5];
  // u = conv(x, w_rel[:, :64])           (no bias, no relu)
  acc_init(acc, 0.f);
  convC_acc<64>(xb, ws + OFF_WTU, o, acc);
#pragma unroll
  for (int y = 0; y < 5; ++y)
#pragma unroll
    for (int xx = 0; xx < 5; ++xx) ws[OFF_U + gout + y * 5 + xx] = acc[y][xx];
  // v = conv(x, w_rel[:, 64:]) + b_rel   (no relu)
  acc_init(acc, b_rel[o]);
  convC_acc<64>(xb, ws + OFF_WTV, o, acc);
#pragma unroll
  for (int y = 0; y < 5; ++y)
#pragma unroll
    for (int xx = 0; xx < 5; ++xx) ws[OFF_V + gout + y * 5 + xx] = acc[y][xx];
  // xs = relu(conv(x, w_self) + b_self)
  acc_init(acc, b_self[o]);
  convC_acc<64>(xb, ws + OFF_WTSELF, o, acc);
#pragma unroll
  for (int y = 0; y < 5; ++y)
#pragma unroll
    for (int xx = 0; xx < 5; ++xx)
      ws[OFF_XS + gout + y * 5 + xx] = fmaxf(acc[y][xx], 0.f);
}

// ---------------- K5: pred combine + aff conv + a + LN partial sums ------
__global__ __launch_bounds__(256) void k5_pred_aff(
    const float* __restrict__ x, const float* __restrict__ b_aff,
    float* __restrict__ ws) {
  __shared__ float pp[4 * IST];
  __shared__ float smr[4][16];
  __shared__ float swt[4];
  __shared__ float wred[4][2];
  int tid = threadIdx.x;
  int img0 = blockIdx.x * 4;
  int b = img0 >> 4;
  for (int i = tid; i < 4 * IST; i += 256) pp[i] = 0.f;
  if (tid < 64) {
    int k = tid >> 4, j = tid & 15;
    smr[k][j] = ws[OFF_SM + (size_t)(img0 + k) * 16 + j];
  }
  if (tid < 4) {
    int n = (img0 + tid) & 15;
    swt[tid] = ws[OFF_SM + (size_t)(img0 + tid) * 16 + n];  // self weight
  }
  __syncthreads();
  const float* u  = ws + OFF_U;
  const float* v  = ws + OFF_V;
  const float* xs = ws + OFF_XS;
  for (int i4 = tid; i4 < 1600; i4 += 256) {   // 4 img * 400 float4
    int k = i4 / 400; int e = (i4 % 400) * 4;
    size_t gi = (size_t)(img0 + k) * IE + e;
    float4 uu = *(const float4*)(u + gi);
    float4 xx = *(const float4*)(xs + gi);
    float sw = swt[k];
    int nk = (img0 + k) & 15;
    float ax = sw * xx.x, ay = sw * xx.y, az = sw * xx.z, aw = sw * xx.w;
#pragma unroll
    for (int j = 0; j < 16; ++j) {
      float wj = (j == nk) ? 0.f : smr[k][j];
      float4 vv = *(const float4*)(v + (size_t)(b * 16 + j) * IE + e);
      ax = fmaf(wj, fmaxf(uu.x + vv.x, 0.f), ax);
      ay = fmaf(wj, fmaxf(uu.y + vv.y, 0.f), ay);
      az = fmaf(wj, fmaxf(uu.z + vv.z, 0.f), az);
      aw = fmaf(wj, fmaxf(uu.w + vv.w, 0.f), aw);
    }
    float vals[4] = {ax, ay, az, aw};
#pragma unroll
    for (int t = 0; t < 4; ++t) {
      int ee = e + t; int c = ee / PIX, pix = ee % PIX;
      pp[k * IST + c * CST + (pix / 5 + 1) * 8 + pix % 5 + 1] = vals[t];
    }
  }
  __syncthreads();
  int wave = tid >> 6, lane = tid & 63;
  int img = lane >> 4, o = wave * 16 + (lane & 15);
  float acc[5][5];
  acc_init(acc, b_aff[o]);
  convC_acc<64>(&pp[img * IST], ws + OFF_WTAFF, o, acc);
  size_t gout = (size_t)(img0 + img) * IE + o * PIX;
  float* aout = ws + OFF_A + gout;
  const float* xg = x + gout;
  float s = 0.f, s2 = 0.f;
#pragma unroll
  for (int y = 0; y < 5; ++y)
#pragma unroll
    for (int xx = 0; xx < 5; ++xx) {
      float a = fmaxf(acc[y][xx], 0.f) + xg[y * 5 + xx];  // a = relu(conv)+s
      aout[y * 5 + xx] = a;
      s += a; s2 = fmaf(a, a, s2);
    }
  for (int off = 32; off > 0; off >>= 1) {
    s  += __shfl_down(s, off, 64);
    s2 += __shfl_down(s2, off, 64);
  }
  if (lane == 0) { wred[wave][0] = s; wred[wave][1] = s2; }
  __syncthreads();
  if (tid == 0) {
    float ts  = wred[0][0] + wred[1][0] + wred[2][0] + wred[3][0];
    float ts2 = wred[0][1] + wred[1][1] + wred[2][1] + wred[3][1];
    atomicAdd(ws + OFF_SUMS + b * 2,     ts);
    atomicAdd(ws + OFF_SUMS + b * 2 + 1, ts2);
  }
}

// ---------------- K6: LayerNorm apply + dual conv agg; 2 images/block ----
__global__ __launch_bounds__(128) void k6_agg(
    const float* __restrict__ x, const float* __restrict__ gamma,
    const float* __restrict__ beta, const float* __restrict__ b_agg,
    float* __restrict__ ws, float* __restrict__ out) {
  __shared__ float ap[2 * IST];
  __shared__ float xq[2 * IST];
  int tid = threadIdx.x;
  int img0 = blockIdx.x * 2;
  int b = img0 >> 4;
  float ssum = ws[OFF_SUMS + b * 2], ssq = ws[OFF_SUMS + b * 2 + 1];
  float mu = ssum * (1.f / 25600.f);
  float var = ssq * (1.f / 25600.f) - mu * mu;
  float rstd = rsqrtf(var + 1e-6f);
  for (int i = tid; i < 2 * IST; i += 128) { ap[i] = 0.f; xq[i] = 0.f; }
  __syncthreads();
  const float* a = ws + OFF_A;
  for (int i = tid; i < 2 * IE; i += 128) {
    int k = i / IE, e = i % IE, c = e / PIX, pix = e % PIX;
    int n = (img0 + k) & 15;
    size_t gi = (size_t)(img0 + k) * IE + e;
    float av = a[gi], xv = x[gi];
    float an = (av - mu) * rstd * gamma[n * IE + e] + beta[n * IE + e];
    int off = k * IST + c * CST + (pix / 5 + 1) * 8 + pix % 5 + 1;
    ap[off] = an; xq[off] = xv;
  }
  __syncthreads();
  int wave = tid >> 6, lane = tid & 63;
  int img = lane >> 5, o = wave * 32 + (lane & 31);
  float acc[5][5];
  acc_init(acc, b_agg[o]);
  convC_acc<64>(&ap[img * IST], ws + OFF_WTAGA, o, acc);
  convC_acc<64>(&xq[img * IST], ws + OFF_WTAGS, o, acc);
  float* op = out + (size_t)(img0 + img) * IE + o * PIX;
#pragma unroll
  for (int y = 0; y < 5; ++y)
#pragma unroll
    for (int xx = 0; xx < 5; ++xx)
      op[y * 5 + xx] = fmaxf(acc[y][xx], 0.f);
}

// ---------------- launch ----------------
extern "C" void kernel_launch(void* const* d_in, const int* in_sizes, int n_in,
                              void* d_out, int out_size, void* d_ws,
                              size_t ws_size, hipStream_t stream) {
  const float* x      = (const float*)d_in[0];
  // d_in[1] = g_idx: deterministic (i-major pairs, gate==1) — folded analytically
  const float* w_rel  = (const float*)d_in[2];
  const float* b_rel  = (const float*)d_in[3];
  const float* w_self = (const float*)d_in[4];
  const float* b_self = (const float*)d_in[5];
  const float* w_aff  = (const float*)d_in[6];
  const float* b_aff  = (const float*)d_in[7];
  const float* w_agg  = (const float*)d_in[8];
  const float* b_agg  = (const float*)d_in[9];
  const float* w_attn = (const float*)d_in[10];
  const float* b_attn = (const float*)d_in[11];
  const float* w_q    = (const float*)d_in[12];
  const float* b_q    = (const float*)d_in[13];
  const float* w_k    = (const float*)d_in[14];
  const float* b_k    = (const float*)d_in[15];
  const float* gamma  = (const float*)d_in[16];
  const float* beta   = (const float*)d_in[17];
  float* ws  = (float*)d_ws;
  float* out = (float*)d_out;

  k0_transpose<<<1256, 256, 0, stream>>>(w_rel, w_self, w_aff, w_agg,
                                         w_q, w_k, w_attn, ws);
  k1_qk<<<IMG / 2, 128, 0, stream>>>(x, b_attn, b_q, b_k, ws);
  k2_attn<<<BB, 256, 0, stream>>>(ws);
  k3_uvxs<<<IMG / 4, 256, 0, stream>>>(x, b_rel, b_self, ws);
  k5_pred_aff<<<IMG / 4, 256, 0, stream>>>(x, b_aff, ws);
  k6_agg<<<IMG / 2, 128, 0, stream>>>(x, gamma, beta, b_agg, ws, out);
}

// Round 5
// 206.941 us; speedup vs baseline: 1.7965x; 1.7965x over previous
//
#include <hip/hip_runtime.h>
#include <hip/hip_bf16.h>

#define DEV static __device__ __forceinline__

typedef short s8v __attribute__((ext_vector_type(8)));
typedef float f16v __attribute__((ext_vector_type(16)));
typedef unsigned short u16;
typedef unsigned int u32;

constexpr int IMG = 1024;            // B*N
constexpr int IE  = 1600;            // 64ch * 25pix
constexpr float INV_TEMP = 0.035355339059327376f;

// ---- bf16 weight region (ushort offsets), k-major layout [o][k], k = t*C + c
constexpr int WU = 0, WV = 36864, WSELF = 73728, WAFF = 110592,
              WAGA = 147456, WAGS = 184320;          // 64x576 each
constexpr int WQ = 221184, WK = 230400;              // 32x288 each
// ---- float offsets in ws
constexpr size_t OFF_Q    = 119808;                  // 1024*800
constexpr size_t OFF_K    = OFF_Q + 819200;
constexpr size_t OFF_U    = OFF_Q;                   // alias: Q,K dead after k2
constexpr size_t OFF_V    = OFF_Q + 1638400;
constexpr size_t OFF_XS   = OFF_V + 1638400;
constexpr size_t OFF_A    = OFF_XS + 1638400;
constexpr size_t OFF_SM   = OFF_A + 1638400;         // 64*256
constexpr size_t OFF_SUMS = OFF_SM + 16384;          // 128
constexpr size_t OFF_WTS  = OFF_SUMS + 128;          // w_attn^T [c][ds] fp32 (2048)

DEV u16 f2bf(float f) {
  u32 u = __float_as_uint(f);
  return (u16)((u + 0x7FFF + ((u >> 16) & 1)) >> 16);
}
DEV int xrow(int p) { return (p / 5 + 1) * 8 + (p % 5 + 1); }
DEV int slotOf(int R) { return (3 * (R >> 3) + (R & 7)) & 7; }
DEV f16v zero16() {
  f16v z;
#pragma unroll
  for (int i = 0; i < 16; ++i) z[i] = 0.f;
  return z;
}
// write channel-pair (c=2cp, 2cp+1) of pixel p as packed bf16 into swizzled xT
DEV void xt_write_pair(u16* xt, int p, int cp, float v0, float v1) {
  int R = xrow(p);
  int chunk = ((cp >> 2) ^ slotOf(R)) & 7;
  u32 u = (u32)f2bf(v0) | ((u32)f2bf(v1) << 16);
  *(u32*)((char*)xt + R * 128 + chunk * 16 + (cp & 3) * 4) = u;
}
// per-lane, per-tap base byte offsets into a 7x8x64ch swizzled xT image
DEV void mk_bases(int lane, int bases[9]) {
  int p = lane & 31; if (p > 24) p = 24;       // cols 25-31: clamped (discarded)
  int hi = lane >> 5;
  int y = p / 5, x = p % 5;
#pragma unroll
  for (int t = 0; t < 9; ++t) {
    int R = (y + t / 3) * 8 + (x + t % 3);
    int sl = slotOf(R);
    bases[t] = R * 128 + (((sl ^ hi) & 7) << 4);
  }
}

// ---------------- K0: weight prep (bf16 k-major) + w_attn transpose ----------
__global__ __launch_bounds__(256) void k0_prep(
    const float* __restrict__ w_rel, const float* __restrict__ w_self,
    const float* __restrict__ w_aff, const float* __restrict__ w_agg,
    const float* __restrict__ w_q, const float* __restrict__ w_k,
    const float* __restrict__ w_attn, float* __restrict__ ws) {
  u16* wb = (u16*)ws;
  int idx = blockIdx.x * 256 + threadIdx.x;
  if (idx < 221184) {
    int reg = idx / 36864, w = idx % 36864;
    int o = w / 576, k = w % 576, t = k >> 6, c = k & 63;
    float v;
    switch (reg) {
      case 0:  v = w_rel[(o * 128 + c) * 9 + t]; break;
      case 1:  v = w_rel[(o * 128 + 64 + c) * 9 + t]; break;
      case 2:  v = w_self[(o * 64 + c) * 9 + t]; break;
      case 3:  v = w_aff[(o * 64 + c) * 9 + t]; break;
      case 4:  v = w_agg[(o * 128 + c) * 9 + t]; break;
      default: v = w_agg[(o * 128 + 64 + c) * 9 + t]; break;
    }
    wb[idx] = f2bf(v);
  } else if (idx < 239616) {
    int i2 = idx - 221184;
    int conv = i2 / 9216, r = i2 % 9216;
    int o = r / 288, k = r % 288, t = k >> 5, c = k & 31;
    const float* src = conv ? w_k : w_q;
    wb[idx] = f2bf(src[(o * 32 + c) * 9 + t]);
  } else if (idx < 239616 + 2048) {
    int i2 = idx - 239616;
    int c = i2 >> 5, ds = i2 & 31;
    ws[OFF_WTS + i2] = w_attn[ds * 64 + c];
  }
}

// ---------------- K1: s2d (1x1, fp32) + q/k 3x3 convs (MFMA); 2 img/block ----
__global__ __launch_bounds__(256, 2) void k1_qk(
    const float* __restrict__ x, const float* __restrict__ b_attn,
    const float* __restrict__ b_q, const float* __restrict__ b_k,
    float* __restrict__ ws) {
  __shared__ float xlin[3200];
  __shared__ float wts[2048];
  __shared__ u16 xt32[2 * 3584];
  const u16* wb = (const u16*)ws;
  int tid = threadIdx.x, lane = tid & 63, wave = tid >> 6, hi = lane >> 5;
  int img0 = blockIdx.x * 2;
  int conv = wave & 1, wimg = wave >> 1;
  int oA = lane & 31;
  const u16* wsrc = wb + (conv ? WK : WQ) + oA * 288 + hi * 8;
  s8v A[18];
#pragma unroll
  for (int s = 0; s < 18; ++s) A[s] = *(const s8v*)(wsrc + s * 16);
  int bases[9]; mk_bases(lane, bases);
  for (int i = tid; i < 3200; i += 256) xlin[i] = x[(size_t)img0 * IE + i];
  for (int i = tid; i < 2048; i += 256) wts[i] = ws[OFF_WTS + i];
  // zero FULL buffer: 2*3584 u16 = 3584 u32  (R4 bug: was 1792 -> img1 halo garbage)
  for (int i = tid; i < 3584; i += 256) ((u32*)xt32)[i] = 0;
  __syncthreads();
  if (tid < 200) {                       // s2d: (img, ds-group of 8, pixel)
    int im = tid / 100, r = tid % 100, dsg = r / 25, p = r % 25;
    float acc[8];
#pragma unroll
    for (int d = 0; d < 8; ++d) acc[d] = b_attn[dsg * 8 + d];
    const float* xp = &xlin[im * IE + p];
#pragma unroll 4
    for (int c = 0; c < 64; ++c) {
      float xv = xp[c * 25];
      const float* wp = &wts[c * 32 + dsg * 8];
#pragma unroll
      for (int d = 0; d < 8; ++d) acc[d] = fmaf(wp[d], xv, acc[d]);
    }
    s8v pk;
#pragma unroll
    for (int d = 0; d < 8; ++d) pk[d] = (short)f2bf(acc[d]);
    int R = xrow(p);
    int chunk = (dsg ^ slotOf(R)) & 7;
    *(s8v*)((char*)xt32 + im * 7168 + R * 128 + chunk * 16) = pk;
  }
  __syncthreads();
  f16v acc = zero16();
  const char* xb = (const char*)xt32 + wimg * 7168;
#pragma unroll
  for (int s = 0; s < 18; ++s) {
    s8v bfr = *(const s8v*)(xb + (bases[s >> 1] ^ ((s & 1) << 5)));
    acc = __builtin_amdgcn_mfma_f32_32x32x16_bf16(A[s], bfr, acc, 0, 0, 0);
  }
  float* outp = ws + (conv ? OFF_K : OFF_Q) + (size_t)(img0 + wimg) * 800;
  const float* bq = conv ? b_k : b_q;
  int p = lane & 31;
  if (p < 25) {
#pragma unroll
    for (int r = 0; r < 16; ++r) {
      int ol = (r & 3) + 8 * (r >> 2) + 4 * hi;
      outp[ol * 25 + p] = fmaxf(acc[r] + bq[ol], 0.f);
    }
  }
}

// ---------------- K2: attn logits + softmax (+ zero LN sums) -----------------
__global__ __launch_bounds__(256) void k2_attn(float* __restrict__ ws) {
  __shared__ float kb[16][804];
  __shared__ float att[16][17];
  __shared__ float rowm[16], rowsum[16];
  int b = blockIdx.x, tid = threadIdx.x;
  const float* kg = ws + OFF_K + (size_t)b * 12800;
  for (int i = tid; i < 12800; i += 256) kb[i / 800][i % 800] = kg[i];
  if (tid < 2) ws[OFF_SUMS + b * 2 + tid] = 0.f;
  __syncthreads();
  int i = tid >> 4, j = tid & 15;
  const float* qr = ws + OFF_Q + (size_t)(b * 16 + i) * 800;
  float acc = 0.f;
  for (int f = 0; f < 800; f += 4) {
    float4 a = *(const float4*)(qr + f);
    float4 c = *(const float4*)&kb[j][f];
    acc += a.x * c.x + a.y * c.y + a.z * c.z + a.w * c.w;
  }
  att[i][j] = acc * INV_TEMP;
  __syncthreads();
  if (tid < 16) {
    float m = att[tid][0];
    for (int jj = 1; jj < 16; ++jj) m = fmaxf(m, att[tid][jj]);
    float s = 0.f;
    for (int jj = 0; jj < 16; ++jj) s += expf(att[tid][jj] - m);
    rowm[tid] = m; rowsum[tid] = 1.f / s;
  }
  __syncthreads();
  ws[OFF_SM + (size_t)b * 256 + tid] = expf(att[i][j] - rowm[i]) * rowsum[i];
}

// ---------------- K3: u, v, xs convs via MFMA; 4 img/block, 6 waves ----------
__global__ __launch_bounds__(384, 2) void k3_uvxs(
    const float* __restrict__ x, const float* __restrict__ b_rel,
    const float* __restrict__ b_self, float* __restrict__ ws) {
  __shared__ float xlin[1600];
  __shared__ u16 xt[3584];
  const u16* wb = (const u16*)ws;
  int tid = threadIdx.x, lane = tid & 63, wave = tid >> 6, hi = lane >> 5;
  int conv = wave >> 1, ot = wave & 1;     // conv: 0=u 1=v 2=self
  int oA = ot * 32 + (lane & 31);
  const u16* wsrc = wb + (conv == 0 ? WU : (conv == 1 ? WV : WSELF)) + oA * 576 + hi * 8;
  s8v A[36];
#pragma unroll
  for (int s = 0; s < 36; ++s) A[s] = *(const s8v*)(wsrc + s * 16);
  int bases[9]; mk_bases(lane, bases);
  // zero FULL buffer: 3584 u16 = 1792 u32  (R4 bug: was 896 -> rows>=28 garbage)
  for (int i = tid; i < 1792; i += 384) ((u32*)xt)[i] = 0;
  int img0 = blockIdx.x * 4;
  size_t obase = conv == 0 ? OFF_U : (conv == 1 ? OFF_V : OFF_XS);
  for (int im = 0; im < 4; ++im) {
    int img = img0 + im;
    __syncthreads();
    for (int i = tid; i < 1600; i += 384) xlin[i] = x[(size_t)img * IE + i];
    __syncthreads();
    for (int i = tid; i < 800; i += 384) {
      int p = i >> 5, cp = i & 31;
      xt_write_pair(xt, p, cp, xlin[cp * 50 + p], xlin[cp * 50 + 25 + p]);
    }
    __syncthreads();
    f16v acc = zero16();
#pragma unroll
    for (int s = 0; s < 36; ++s) {
      s8v bfr = *(const s8v*)((const char*)xt + (bases[s >> 2] ^ ((s & 3) << 5)));
      acc = __builtin_amdgcn_mfma_f32_32x32x16_bf16(A[s], bfr, acc, 0, 0, 0);
    }
    int p = lane & 31;
    if (p < 25) {
      float* outp = ws + obase + (size_t)img * IE;
#pragma unroll
      for (int r = 0; r < 16; ++r) {
        int ol = ot * 32 + (r & 3) + 8 * (r >> 2) + 4 * hi;
        float v = acc[r];
        if (conv == 1) v += b_rel[ol];
        if (conv == 2) v = fmaxf(v + b_self[ol], 0.f);
        outp[ol * 25 + p] = v;
      }
    }
  }
}

// ---------------- K5: pred combine + aff conv (MFMA) + a + LN sums -----------
__global__ __launch_bounds__(256, 2) void k5_pred_aff(
    const float* __restrict__ x, const float* __restrict__ b_aff,
    float* __restrict__ ws) {
  __shared__ float predlin[2][1600];
  __shared__ u16 xt[2][3584];
  __shared__ float smr[2][16];
  __shared__ float selfw[2];
  const u16* wb = (const u16*)ws;
  int tid = threadIdx.x, lane = tid & 63, wave = tid >> 6, hi = lane >> 5;
  int img0 = blockIdx.x * 2, bat = img0 >> 4;
  int wimg = wave >> 1, ot = wave & 1;
  int oA = ot * 32 + (lane & 31);
  const u16* wsrc = wb + WAFF + oA * 576 + hi * 8;
  s8v A[36];
#pragma unroll
  for (int s = 0; s < 36; ++s) A[s] = *(const s8v*)(wsrc + s * 16);
  int bases[9]; mk_bases(lane, bases);
  // zero FULL buffer: 2*3584 u16 = 3584 u32  (R4 bug: was 1792)
  for (int i = tid; i < 3584; i += 256) ((u32*)&xt[0][0])[i] = 0;
  if (tid < 32) { int k = tid >> 4, j = tid & 15; smr[k][j] = ws[OFF_SM + (size_t)(img0 + k) * 16 + j]; }
  if (tid < 2)  { int n = (img0 + tid) & 15; selfw[tid] = ws[OFF_SM + (size_t)(img0 + tid) * 16 + n]; }
  __syncthreads();
  const float* U = ws + OFF_U; const float* V = ws + OFF_V; const float* XS = ws + OFF_XS;
  for (int i4 = tid; i4 < 800; i4 += 256) {
    int im = i4 / 400, e = (i4 % 400) * 4;
    size_t gi = (size_t)(img0 + im) * IE + e;
    float4 uu = *(const float4*)(U + gi);
    float4 xx = *(const float4*)(XS + gi);
    float sw = selfw[im];
    int nk = (img0 + im) & 15;
    float ax = sw * xx.x, ay = sw * xx.y, az = sw * xx.z, aw = sw * xx.w;
#pragma unroll
    for (int j = 0; j < 16; ++j) {
      float wj = (j == nk) ? 0.f : smr[im][j];
      float4 vv = *(const float4*)(V + (size_t)(bat * 16 + j) * IE + e);
      ax = fmaf(wj, fmaxf(uu.x + vv.x, 0.f), ax);
      ay = fmaf(wj, fmaxf(uu.y + vv.y, 0.f), ay);
      az = fmaf(wj, fmaxf(uu.z + vv.z, 0.f), az);
      aw = fmaf(wj, fmaxf(uu.w + vv.w, 0.f), aw);
    }
    *(float4*)&predlin[im][e] = make_float4(ax, ay, az, aw);
  }
  __syncthreads();
  for (int i = tid; i < 1600; i += 256) {
    int im = i / 800, r = i % 800, p = r >> 5, cp = r & 31;
    xt_write_pair(&xt[im][0], p, cp, predlin[im][cp * 50 + p], predlin[im][cp * 50 + 25 + p]);
  }
  __syncthreads();
  f16v acc = zero16();
  const char* xb = (const char*)&xt[wimg][0];
#pragma unroll
  for (int s = 0; s < 36; ++s) {
    s8v bfr = *(const s8v*)(xb + (bases[s >> 2] ^ ((s & 3) << 5)));
    acc = __builtin_amdgcn_mfma_f32_32x32x16_bf16(A[s], bfr, acc, 0, 0, 0);
  }
  int p = lane & 31;
  float s1 = 0.f, s2 = 0.f;
  float* aout = ws + OFF_A + (size_t)(img0 + wimg) * IE;
  const float* xg = x + (size_t)(img0 + wimg) * IE;
  if (p < 25) {
#pragma unroll
    for (int r = 0; r < 16; ++r) {
      int ol = ot * 32 + (r & 3) + 8 * (r >> 2) + 4 * hi;
      float a = fmaxf(acc[r] + b_aff[ol], 0.f) + xg[ol * 25 + p];
      aout[ol * 25 + p] = a;
      s1 += a; s2 = fmaf(a, a, s2);
    }
  }
  for (int off = 32; off; off >>= 1) {
    s1 += __shfl_down(s1, off, 64);
    s2 += __shfl_down(s2, off, 64);
  }
  if (lane == 0) {
    atomicAdd(ws + OFF_SUMS + bat * 2, s1);
    atomicAdd(ws + OFF_SUMS + bat * 2 + 1, s2);
  }
}

// ---------------- K6: LN apply + dual-K agg conv (MFMA); 2 img/block ---------
__global__ __launch_bounds__(256, 2) void k6_agg(
    const float* __restrict__ x, const float* __restrict__ gamma,
    const float* __restrict__ beta, const float* __restrict__ b_agg,
    float* __restrict__ ws, float* __restrict__ out) {
  __shared__ float alin[2][1600];
  __shared__ float xlin[2][1600];
  __shared__ u16 xta[2][3584];
  __shared__ u16 xtx[2][3584];
  __shared__ float pbuf[4][1024];
  const u16* wb = (const u16*)ws;
  int tid = threadIdx.x, lane = tid & 63, wave = tid >> 6, hi = lane >> 5;
  int img0 = blockIdx.x * 2, bat = img0 >> 4;
  int ot = wave >> 1, h = wave & 1;        // h=0: a_norm half, h=1: s half
  int oA = ot * 32 + (lane & 31);
  const u16* wsrc = wb + (h ? WAGS : WAGA) + oA * 576 + hi * 8;
  s8v A[36];
#pragma unroll
  for (int s = 0; s < 36; ++s) A[s] = *(const s8v*)(wsrc + s * 16);
  int bases[9]; mk_bases(lane, bases);
  float ssum = ws[OFF_SUMS + bat * 2], ssq = ws[OFF_SUMS + bat * 2 + 1];
  float mu = ssum * (1.f / 25600.f);
  float var = ssq * (1.f / 25600.f) - mu * mu;
  float rstd = rsqrtf(var + 1e-6f);
  // zero FULL buffers: each 2*3584 u16 = 3584 u32  (R4 bug: was 1792)
  for (int i = tid; i < 3584; i += 256) { ((u32*)&xta[0][0])[i] = 0; ((u32*)&xtx[0][0])[i] = 0; }
  float* al = &alin[0][0]; float* xl = &xlin[0][0];
  const float* ag = ws + OFF_A + (size_t)img0 * IE;
  const float* xg = x + (size_t)img0 * IE;
  for (int i = tid; i < 3200; i += 256) { al[i] = ag[i]; xl[i] = xg[i]; }
  __syncthreads();
  for (int i = tid; i < 1600; i += 256) {
    int im = i / 800, r = i % 800, p = r >> 5, cp = r & 31;
    int n = (img0 + im) & 15;
    int e0 = cp * 50 + p, e1 = e0 + 25;
    float a0 = al[im * 1600 + e0], a1 = al[im * 1600 + e1];
    float an0 = (a0 - mu) * rstd * gamma[(size_t)n * IE + e0] + beta[(size_t)n * IE + e0];
    float an1 = (a1 - mu) * rstd * gamma[(size_t)n * IE + e1] + beta[(size_t)n * IE + e1];
    xt_write_pair(&xta[im][0], p, cp, an0, an1);
    xt_write_pair(&xtx[im][0], p, cp, xl[im * 1600 + e0], xl[im * 1600 + e1]);
  }
  __syncthreads();
  const char* bsrc = h ? (const char*)&xtx[0][0] : (const char*)&xta[0][0];
  f16v acc0 = zero16(), acc1 = zero16();
#pragma unroll
  for (int s = 0; s < 36; ++s) {
    s8v bfr = *(const s8v*)(bsrc + (bases[s >> 2] ^ ((s & 3) << 5)));
    acc0 = __builtin_amdgcn_mfma_f32_32x32x16_bf16(A[s], bfr, acc0, 0, 0, 0);
  }
#pragma unroll
  for (int s = 0; s < 36; ++s) {
    s8v bfr = *(const s8v*)(bsrc + 7168 + (bases[s >> 2] ^ ((s & 3) << 5)));
    acc1 = __builtin_amdgcn_mfma_f32_32x32x16_bf16(A[s], bfr, acc1, 0, 0, 0);
  }
  int p = lane & 31;
  if (h == 1) {
#pragma unroll
    for (int r = 0; r < 16; ++r) {
      int ol = (r & 3) + 8 * (r >> 2) + 4 * hi;
      pbuf[0 + ot][ol * 32 + p] = acc0[r];
      pbuf[2 + ot][ol * 32 + p] = acc1[r];
    }
  }
  __syncthreads();
  if (h == 0 && p < 25) {
#pragma unroll
    for (int r = 0; r < 16; ++r) {
      int ol = (r & 3) + 8 * (r >> 2) + 4 * hi;
      int o = ot * 32 + ol;
      float v0 = acc0[r] + pbuf[0 + ot][ol * 32 + p] + b_agg[o];
      float v1 = acc1[r] + pbuf[2 + ot][ol * 32 + p] + b_agg[o];
      out[(size_t)(img0 + 0) * IE + o * 25 + p] = fmaxf(v0, 0.f);
      out[(size_t)(img0 + 1) * IE + o * 25 + p] = fmaxf(v1, 0.f);
    }
  }
}

// ---------------- launch ----------------
extern "C" void kernel_launch(void* const* d_in, const int* in_sizes, int n_in,
                              void* d_out, int out_size, void* d_ws,
                              size_t ws_size, hipStream_t stream) {
  const float* x      = (const float*)d_in[0];
  // d_in[1] = g_idx: deterministic (i-major pairs, gate==1) — folded analytically
  const float* w_rel  = (const float*)d_in[2];
  const float* b_rel  = (const float*)d_in[3];
  const float* w_self = (const float*)d_in[4];
  const float* b_self = (const float*)d_in[5];
  const float* w_aff  = (const float*)d_in[6];
  const float* b_aff  = (const float*)d_in[7];
  const float* w_agg  = (const float*)d_in[8];
  const float* b_agg  = (const float*)d_in[9];
  const float* w_attn = (const float*)d_in[10];
  const float* b_attn = (const float*)d_in[11];
  const float* w_q    = (const float*)d_in[12];
  const float* b_q    = (const float*)d_in[13];
  const float* w_k    = (const float*)d_in[14];
  const float* b_k    = (const float*)d_in[15];
  const float* gamma  = (const float*)d_in[16];
  const float* beta   = (const float*)d_in[17];
  float* ws  = (float*)d_ws;
  float* out = (float*)d_out;

  k0_prep<<<944, 256, 0, stream>>>(w_rel, w_self, w_aff, w_agg, w_q, w_k, w_attn, ws);
  k1_qk<<<IMG / 2, 256, 0, stream>>>(x, b_attn, b_q, b_k, ws);
  k2_attn<<<64, 256, 0, stream>>>(ws);
  k3_uvxs<<<IMG / 4, 384, 0, stream>>>(x, b_rel, b_self, ws);
  k5_pred_aff<<<IMG / 2, 256, 0, stream>>>(x, b_aff, ws);
  k6_agg<<<IMG / 2, 256, 0, stream>>>(x, gamma, beta, b_agg, ws, out);
}